// Round 3
// baseline (143.338 us; speedup 1.0000x reference)
//
#include <hip/hip_runtime.h>
#include <hip/hip_bf16.h>

typedef __bf16 bf16x8 __attribute__((ext_vector_type(8)));
typedef float f32x4 __attribute__((ext_vector_type(4)));

#define NB 8
#define NT 2048
#define NC 1024
#define NH 64

__device__ __forceinline__ unsigned short bfbits(float f) {
    return __builtin_bit_cast(unsigned short, (__bf16)f);
}

// ---------------- kernel 1: W -> W^T (bf16) ----------------
// Wt layout: [3][64][1024], order 0=Wq, 1=Wk, 2=Wv
__global__ __launch_bounds__(256) void wt_kernel(const float* __restrict__ Wq,
                                                 const float* __restrict__ Wk,
                                                 const float* __restrict__ Wv,
                                                 unsigned short* __restrict__ Wt) {
    int idx = blockIdx.x * 256 + threadIdx.x;   // 0 .. 196608
    int n = idx >> 16;
    int r = idx & 65535;
    int c = r >> 6;       // 0..1023
    int h = r & 63;       // coalesced reads over h
    const float* W = (n == 0) ? Wq : ((n == 1) ? Wk : Wv);
    float x = W[c * 64 + h];
    Wt[(n << 16) + h * 1024 + c] = bfbits(x);
}

// ---------------- kernel 2: fused QKV projection, split-K=2, fp32 partials ----------------
// wave = 16 rows x 64 cols x 512 k's. Partial layout per slice (1048576 f32 per type):
//   type0 (Q): [b][t][h]   type1 (K): [b][t][h]   type2 (V^T): [b][h][t]
__global__ __launch_bounds__(256, 4) void proj_kernel(const float* __restrict__ Xv,
                                                      const float* __restrict__ Xk,
                                                      const float* __restrict__ Xq,
                                                      const unsigned short* __restrict__ Wt,
                                                      float* __restrict__ P) {
    int wid  = blockIdx.x * 4 + (threadIdx.x >> 6);   // 0..6143
    int lane = threadIdx.x & 63;
    int slice = wid & 1;
    int rest  = wid >> 1;
    int type = rest >> 10;         // 0=Q,1=K,2=V
    int tile = rest & 1023;        // 1024 tiles of 16 rows
    int b    = tile >> 7;
    int t0   = (tile & 127) << 4;
    const float* X = (type == 0) ? Xq : ((type == 1) ? Xk : Xv);
    const unsigned short* W = Wt + (type << 16);
    int lo = lane & 15, hi = lane >> 4;

    const float* xrow = X + (size_t)(b * NT + t0 + lo) * NC + hi * 8;
    f32x4 acc[4];
#pragma unroll
    for (int ct = 0; ct < 4; ++ct) acc[ct] = 0.f;

    int kbeg = slice << 9;          // 0 or 512
    for (int k0 = kbeg; k0 < kbeg + 512; k0 += 128) {
        // batch-issue 8 independent 16B loads (4 k-steps worth)
        float4 x[8];
#pragma unroll
        for (int u = 0; u < 4; ++u) {
            x[2 * u]     = *(const float4*)(xrow + k0 + 32 * u);
            x[2 * u + 1] = *(const float4*)(xrow + k0 + 32 * u + 4);
        }
#pragma unroll
        for (int u = 0; u < 4; ++u) {
            bf16x8 av;
            av[0] = (__bf16)x[2*u].x; av[1] = (__bf16)x[2*u].y;
            av[2] = (__bf16)x[2*u].z; av[3] = (__bf16)x[2*u].w;
            av[4] = (__bf16)x[2*u+1].x; av[5] = (__bf16)x[2*u+1].y;
            av[6] = (__bf16)x[2*u+1].z; av[7] = (__bf16)x[2*u+1].w;
            const unsigned short* wp = W + lo * 1024 + k0 + 32 * u + hi * 8;
#pragma unroll
            for (int ct = 0; ct < 4; ++ct) {
                bf16x8 bv = *(const bf16x8*)(wp + ct * 16 * 1024);
                acc[ct] = __builtin_amdgcn_mfma_f32_16x16x32_bf16(av, bv, acc[ct], 0, 0, 0);
            }
        }
    }

    float* Ps = P + (size_t)slice * 3145728 + (size_t)type * 1048576;
    if (type < 2) {
#pragma unroll
        for (int ct = 0; ct < 4; ++ct)
#pragma unroll
            for (int r = 0; r < 4; ++r) {
                int t = t0 + hi * 4 + r;
                int h = lo + 16 * ct;
                Ps[(size_t)(b * NT + t) * NH + h] = acc[ct][r];
            }
    } else {
#pragma unroll
        for (int ct = 0; ct < 4; ++ct) {
            int h = lo + 16 * ct;
            *(float4*)(Ps + (size_t)(b * NH + h) * NT + t0 + hi * 4) =
                make_float4(acc[ct][0], acc[ct][1], acc[ct][2], acc[ct][3]);
        }
    }
}

// ---------------- kernel 2b: combine split-K partials -> bf16 ----------------
__global__ __launch_bounds__(256) void combine_kernel(const float* __restrict__ P,
                                                      unsigned short* __restrict__ OUT) {
    int i = blockIdx.x * 256 + threadIdx.x;    // 0 .. 786431 (x4 floats)
    float4 a = *(const float4*)(P + 4 * (size_t)i);
    float4 c = *(const float4*)(P + 3145728 + 4 * (size_t)i);
    ushort4 o;
    o.x = bfbits(a.x + c.x);
    o.y = bfbits(a.y + c.y);
    o.z = bfbits(a.z + c.z);
    o.w = bfbits(a.w + c.w);
    *(ushort4*)(OUT + 4 * (size_t)i) = o;
}

// ---------------- kernel 3: causal flash attention (MFMA) ----------------
// block = 4 waves, one 16-row Q-tile, 4-way split of the s-range + LDS merge
__global__ __launch_bounds__(256) void attn_kernel(const unsigned short* __restrict__ Q,
                                                   const unsigned short* __restrict__ K,
                                                   const unsigned short* __restrict__ VT,
                                                   float* __restrict__ out) {
    __shared__ __align__(16) unsigned short p_lds[4 * 512];   // per-wave 16x32 bf16 P
    __shared__ __align__(16) float acc_lds[4 * 16 * 64];
    __shared__ float m_lds[4][16];
    __shared__ float l_lds[4][16];

    int b  = blockIdx.x >> 7;
    int qt = blockIdx.x & 127;
    int q0 = qt << 4;
    int w    = threadIdx.x >> 6;
    int lane = threadIdx.x & 63;
    int lo = lane & 15, hi = lane >> 4;

    const unsigned short* qb = Q + (size_t)(b * NT + q0 + lo) * NH + hi * 8;
    bf16x8 qf0 = *(const bf16x8*)(qb);
    bf16x8 qf1 = *(const bf16x8*)(qb + 32);

    int Ctot = (q0 + 16 + 31) >> 5;              // ceil((q0+16)/32) 32-wide s-chunks
    int c0 = (Ctot * w) >> 2;
    int c1 = (Ctot * (w + 1)) >> 2;

    float m[4], l[4];
    f32x4 acc[4];
#pragma unroll
    for (int r = 0; r < 4; ++r) { m[r] = -1e30f; l[r] = 0.f; }
#pragma unroll
    for (int ct = 0; ct < 4; ++ct) acc[ct] = 0.f;

    const float SC = 0.03125f * 1.44269504088896340736f;  // (C^-0.5) * log2(e)
    unsigned short* pl = p_lds + w * 512;

    for (int c = c0; c < c1; ++c) {
        int s0 = c << 5;
        const unsigned short* kb = K + (size_t)(b * NT + s0 + lo) * NH + hi * 8;
        f32x4 S0 = 0.f, S1 = 0.f;
        S0 = __builtin_amdgcn_mfma_f32_16x16x32_bf16(qf0, *(const bf16x8*)(kb), S0, 0, 0, 0);
        S0 = __builtin_amdgcn_mfma_f32_16x16x32_bf16(qf1, *(const bf16x8*)(kb + 32), S0, 0, 0, 0);
        S1 = __builtin_amdgcn_mfma_f32_16x16x32_bf16(qf0, *(const bf16x8*)(kb + 16 * NH), S1, 0, 0, 0);
        S1 = __builtin_amdgcn_mfma_f32_16x16x32_bf16(qf1, *(const bf16x8*)(kb + 16 * NH + 32), S1, 0, 0, 0);

        int s_a = s0 + lo, s_b = s0 + 16 + lo;
        float z0[4], z1[4], mt[4];
#pragma unroll
        for (int r = 0; r < 4; ++r) {
            int qi = q0 + hi * 4 + r;
            z0[r] = (s_a <= qi) ? S0[r] * SC : -1e30f;
            z1[r] = (s_b <= qi) ? S1[r] * SC : -1e30f;
            mt[r] = fmaxf(z0[r], z1[r]);
        }
#pragma unroll
        for (int d = 1; d < 16; d <<= 1)
#pragma unroll
            for (int r = 0; r < 4; ++r)
                mt[r] = fmaxf(mt[r], __shfl_xor(mt[r], d, 16));

        float p0[4], p1[4], rs[4];
#pragma unroll
        for (int r = 0; r < 4; ++r) {
            float mn = fmaxf(m[r], mt[r]);
            float al = exp2f(m[r] - mn);
            int qi = q0 + hi * 4 + r;
            p0[r] = (s_a <= qi) ? exp2f(z0[r] - mn) : 0.f;
            p1[r] = (s_b <= qi) ? exp2f(z1[r] - mn) : 0.f;
            rs[r] = p0[r] + p1[r];
            m[r] = mn;
            l[r] *= al;
            acc[0][r] *= al; acc[1][r] *= al; acc[2][r] *= al; acc[3][r] *= al;
        }
#pragma unroll
        for (int d = 1; d < 16; d <<= 1)
#pragma unroll
            for (int r = 0; r < 4; ++r)
                rs[r] += __shfl_xor(rs[r], d, 16);
#pragma unroll
        for (int r = 0; r < 4; ++r) {
            l[r] += rs[r];
            int ql = hi * 4 + r;
            pl[ql * 32 + lo]      = bfbits(p0[r]);
            pl[ql * 32 + 16 + lo] = bfbits(p1[r]);
        }
        // P transpose via wave-private LDS -> PV A-frag (compiler inserts lgkmcnt)
        bf16x8 pa = *(const bf16x8*)(pl + lo * 32 + hi * 8);
        const unsigned short* vb = VT + (size_t)(b * NH + lo) * NT + s0 + hi * 8;
#pragma unroll
        for (int ct = 0; ct < 4; ++ct) {
            bf16x8 vv = *(const bf16x8*)(vb + ct * 16 * NT);
            acc[ct] = __builtin_amdgcn_mfma_f32_16x16x32_bf16(pa, vv, acc[ct], 0, 0, 0);
        }
    }

    // dump per-wave partial state
#pragma unroll
    for (int r = 0; r < 4; ++r) {
        int ql = hi * 4 + r;
#pragma unroll
        for (int ct = 0; ct < 4; ++ct)
            acc_lds[(w * 16 + ql) * 64 + lo + 16 * ct] = acc[ct][r];
    }
    if (lo == 0) {
#pragma unroll
        for (int r = 0; r < 4; ++r) {
            m_lds[w][hi * 4 + r] = m[r];
            l_lds[w][hi * 4 + r] = l[r];
        }
    }
    __syncthreads();

    // merge 4 s-splits: thread -> (q, 4 h's)
    int q  = threadIdx.x >> 4;
    int h0 = (threadIdx.x & 15) << 2;
    float M = fmaxf(fmaxf(m_lds[0][q], m_lds[1][q]), fmaxf(m_lds[2][q], m_lds[3][q]));
    float L = 0.f;
    float ox = 0.f, oy = 0.f, oz = 0.f, ow = 0.f;
#pragma unroll
    for (int ww = 0; ww < 4; ++ww) {
        float a_ = exp2f(m_lds[ww][q] - M);
        L += a_ * l_lds[ww][q];
        const float* p = acc_lds + (ww * 16 + q) * 64 + h0;
        ox += a_ * p[0]; oy += a_ * p[1]; oz += a_ * p[2]; ow += a_ * p[3];
    }
    float inv = 1.0f / L;
    float4 res = make_float4(ox * inv, oy * inv, oz * inv, ow * inv);
    *(float4*)(out + (size_t)(b * NT + q0 + q) * NH + h0) = res;
}

extern "C" void kernel_launch(void* const* d_in, const int* in_sizes, int n_in,
                              void* d_out, int out_size, void* d_ws, size_t ws_size,
                              hipStream_t stream) {
    const float* values  = (const float*)d_in[0];
    const float* keys    = (const float*)d_in[1];
    const float* queries = (const float*)d_in[2];
    const float* Wk = (const float*)d_in[3];
    const float* Wq = (const float*)d_in[4];
    const float* Wv = (const float*)d_in[5];
    float* out = (float*)d_out;

    unsigned short* Wt = (unsigned short*)d_ws;        // 196608 ushorts
    unsigned short* Qb = Wt + 196608;                  // Q,K,VT contiguous: 3x1048576
    unsigned short* Kb = Qb + 1048576;
    unsigned short* VT = Kb + 1048576;
    float* P = (float*)(VT + 1048576);                 // 2 x 3145728 fp32 partials (~25 MB)

    wt_kernel<<<768, 256, 0, stream>>>(Wq, Wk, Wv, Wt);
    proj_kernel<<<1536, 256, 0, stream>>>(values, keys, queries, Wt, P);
    combine_kernel<<<3072, 256, 0, stream>>>(P, Qb);
    attn_kernel<<<1024, 256, 0, stream>>>(Qb, Kb, VT, out);
}

// Round 4
// 101.545 us; speedup vs baseline: 1.4116x; 1.4116x over previous
//
#include <hip/hip_runtime.h>
#include <hip/hip_bf16.h>

typedef __bf16 bf16x8 __attribute__((ext_vector_type(8)));
typedef float f32x4 __attribute__((ext_vector_type(4)));
typedef unsigned short u16x8 __attribute__((ext_vector_type(8)));

#define NB 8
#define NT 2048
#define NC 1024
#define NH 64

__device__ __forceinline__ unsigned short bfbits(float f) {
    return __builtin_bit_cast(unsigned short, (__bf16)f);
}

// ---------------- kernel 1: W -> W^T (bf16) ----------------
// Wt layout: [3][64][1024], order 0=Wq, 1=Wk, 2=Wv
__global__ __launch_bounds__(256) void wt_kernel(const float* __restrict__ Wq,
                                                 const float* __restrict__ Wk,
                                                 const float* __restrict__ Wv,
                                                 unsigned short* __restrict__ Wt) {
    int idx = blockIdx.x * 256 + threadIdx.x;   // 0 .. 196608
    int n = idx >> 16;
    int r = idx & 65535;
    int c = r >> 6;       // 0..1023
    int h = r & 63;       // coalesced reads over h
    const float* W = (n == 0) ? Wq : ((n == 1) ? Wk : Wv);
    float x = W[c * 64 + h];
    Wt[(n << 16) + h * 1024 + c] = bfbits(x);
}

// ---------------- kernel 2: LDS-staged tiled QKV projection ----------------
// block = 256 thr (4 waves), BM=64 rows, BK=128, K=1024 (8 chunks)
// LDS: Xs[64][128] bf16 + Ws[64][128] bf16, both XOR-swizzled (byte ^= (row&7)<<4)
// outputs: Q,K bf16 [row][64]; V^T bf16 [b][64][2048]
__global__ __launch_bounds__(256, 4) void proj_kernel(const float* __restrict__ Xv,
                                                      const float* __restrict__ Xk,
                                                      const float* __restrict__ Xq,
                                                      const unsigned short* __restrict__ Wt,
                                                      unsigned short* __restrict__ Q,
                                                      unsigned short* __restrict__ K,
                                                      unsigned short* __restrict__ VT) {
    __shared__ __align__(16) char Xs[64 * 256];   // 64 rows x 128 bf16 (256B/row)
    __shared__ __align__(16) char Ws[64 * 256];

    int type = blockIdx.x >> 8;          // 0=Q,1=K,2=V
    int mt   = blockIdx.x & 255;         // 64-row tile index over 16384 rows
    int row0 = mt << 6;
    const float* X = (type == 0) ? Xq : ((type == 1) ? Xk : Xv);
    const unsigned short* W = Wt + (type << 16);

    int tid  = threadIdx.x;
    int w    = tid >> 6;
    int lane = tid & 63;
    int lo = lane & 15, hi = lane >> 4;

    f32x4 acc[4];
#pragma unroll
    for (int ct = 0; ct < 4; ++ct) acc[ct] = 0.f;

    for (int kc = 0; kc < 8; ++kc) {
        // ---- issue stage loads (overlaps previous chunk's MFMA) ----
        float4 xr[8];
#pragma unroll
        for (int i = 0; i < 8; ++i) {
            int f4 = tid + 256 * i;              // 0..2047 over [64 rows][32 f4]
            int r  = f4 >> 5, c4 = f4 & 31;
            xr[i] = *(const float4*)(X + (size_t)(row0 + r) * NC + kc * 128 + c4 * 4);
        }
        u16x8 wr_[4];
#pragma unroll
        for (int i = 0; i < 4; ++i) {
            int s16 = tid + 256 * i;             // 0..1023 over [64 h][16 slots]
            int h = s16 >> 4, sl = s16 & 15;
            wr_[i] = *(const u16x8*)(W + h * 1024 + kc * 128 + sl * 8);
        }
        __syncthreads();   // all waves done reading previous chunk's LDS
        // ---- convert + swizzled LDS writes ----
#pragma unroll
        for (int i = 0; i < 8; ++i) {
            int f4 = tid + 256 * i;
            int r  = f4 >> 5, c4 = f4 & 31;
            ushort4 bv;
            bv.x = bfbits(xr[i].x); bv.y = bfbits(xr[i].y);
            bv.z = bfbits(xr[i].z); bv.w = bfbits(xr[i].w);
            int byte = r * 256 + ((c4 * 8) ^ ((r & 7) << 4));
            *(ushort4*)(Xs + byte) = bv;
        }
#pragma unroll
        for (int i = 0; i < 4; ++i) {
            int s16 = tid + 256 * i;
            int h = s16 >> 4, sl = s16 & 15;
            int byte = h * 256 + ((sl * 16) ^ ((h & 7) << 4));
            *(u16x8*)(Ws + byte) = wr_[i];
        }
        __syncthreads();
        // ---- 4 k-steps of 32 ----
#pragma unroll
        for (int ks = 0; ks < 4; ++ks) {
            int coff = (ks * 64 + hi * 16) ^ ((lo & 7) << 4);
            bf16x8 af = *(const bf16x8*)(Xs + (w * 16 + lo) * 256 + coff);
#pragma unroll
            for (int ct = 0; ct < 4; ++ct) {
                bf16x8 bf = *(const bf16x8*)(Ws + (ct * 16 + lo) * 256 + coff);
                acc[ct] = __builtin_amdgcn_mfma_f32_16x16x32_bf16(af, bf, acc[ct], 0, 0, 0);
            }
        }
    }

    // ---- epilogue ----
    if (type < 2) {
        unsigned short* O = (type == 0) ? Q : K;
#pragma unroll
        for (int ct = 0; ct < 4; ++ct)
#pragma unroll
            for (int r = 0; r < 4; ++r) {
                int row = row0 + w * 16 + hi * 4 + r;
                int h = lo + 16 * ct;
                O[(size_t)row * NH + h] = bfbits(acc[ct][r]);
            }
    } else {
        int trow = row0 + w * 16 + hi * 4;       // 4-aligned
        int b = trow >> 11;
        int t = trow & 2047;
#pragma unroll
        for (int ct = 0; ct < 4; ++ct) {
            int h = lo + 16 * ct;
            ushort4 pk;
            pk.x = bfbits(acc[ct][0]);
            pk.y = bfbits(acc[ct][1]);
            pk.z = bfbits(acc[ct][2]);
            pk.w = bfbits(acc[ct][3]);
            *(ushort4*)(VT + (size_t)(b * NH + h) * NT + t) = pk;
        }
    }
}

// ---------------- kernel 3: causal flash attention (MFMA) ----------------
// block = 4 waves, one 16-row Q-tile, 4-way split of the s-range + LDS merge
__global__ __launch_bounds__(256) void attn_kernel(const unsigned short* __restrict__ Q,
                                                   const unsigned short* __restrict__ K,
                                                   const unsigned short* __restrict__ VT,
                                                   float* __restrict__ out) {
    __shared__ __align__(16) unsigned short p_lds[4 * 512];   // per-wave 16x32 bf16 P
    __shared__ __align__(16) float acc_lds[4 * 16 * 64];
    __shared__ float m_lds[4][16];
    __shared__ float l_lds[4][16];

    int b  = blockIdx.x >> 7;
    int qt = blockIdx.x & 127;
    int q0 = qt << 4;
    int w    = threadIdx.x >> 6;
    int lane = threadIdx.x & 63;
    int lo = lane & 15, hi = lane >> 4;

    const unsigned short* qb = Q + (size_t)(b * NT + q0 + lo) * NH + hi * 8;
    bf16x8 qf0 = *(const bf16x8*)(qb);
    bf16x8 qf1 = *(const bf16x8*)(qb + 32);

    int Ctot = (q0 + 16 + 31) >> 5;              // ceil((q0+16)/32) 32-wide s-chunks
    int c0 = (Ctot * w) >> 2;
    int c1 = (Ctot * (w + 1)) >> 2;

    float m[4], l[4];
    f32x4 acc[4];
#pragma unroll
    for (int r = 0; r < 4; ++r) { m[r] = -1e30f; l[r] = 0.f; }
#pragma unroll
    for (int ct = 0; ct < 4; ++ct) acc[ct] = 0.f;

    const float SC = 0.03125f * 1.44269504088896340736f;  // (C^-0.5) * log2(e)
    unsigned short* pl = p_lds + w * 512;

    for (int c = c0; c < c1; ++c) {
        int s0 = c << 5;
        const unsigned short* kb = K + (size_t)(b * NT + s0 + lo) * NH + hi * 8;
        f32x4 S0 = 0.f, S1 = 0.f;
        S0 = __builtin_amdgcn_mfma_f32_16x16x32_bf16(qf0, *(const bf16x8*)(kb), S0, 0, 0, 0);
        S0 = __builtin_amdgcn_mfma_f32_16x16x32_bf16(qf1, *(const bf16x8*)(kb + 32), S0, 0, 0, 0);
        S1 = __builtin_amdgcn_mfma_f32_16x16x32_bf16(qf0, *(const bf16x8*)(kb + 16 * NH), S1, 0, 0, 0);
        S1 = __builtin_amdgcn_mfma_f32_16x16x32_bf16(qf1, *(const bf16x8*)(kb + 16 * NH + 32), S1, 0, 0, 0);

        int s_a = s0 + lo, s_b = s0 + 16 + lo;
        float z0[4], z1[4], mt[4];
#pragma unroll
        for (int r = 0; r < 4; ++r) {
            int qi = q0 + hi * 4 + r;
            z0[r] = (s_a <= qi) ? S0[r] * SC : -1e30f;
            z1[r] = (s_b <= qi) ? S1[r] * SC : -1e30f;
            mt[r] = fmaxf(z0[r], z1[r]);
        }
#pragma unroll
        for (int d = 1; d < 16; d <<= 1)
#pragma unroll
            for (int r = 0; r < 4; ++r)
                mt[r] = fmaxf(mt[r], __shfl_xor(mt[r], d, 16));

        float p0[4], p1[4], rs[4];
#pragma unroll
        for (int r = 0; r < 4; ++r) {
            float mn = fmaxf(m[r], mt[r]);
            float al = exp2f(m[r] - mn);
            int qi = q0 + hi * 4 + r;
            p0[r] = (s_a <= qi) ? exp2f(z0[r] - mn) : 0.f;
            p1[r] = (s_b <= qi) ? exp2f(z1[r] - mn) : 0.f;
            rs[r] = p0[r] + p1[r];
            m[r] = mn;
            l[r] *= al;
            acc[0][r] *= al; acc[1][r] *= al; acc[2][r] *= al; acc[3][r] *= al;
        }
#pragma unroll
        for (int d = 1; d < 16; d <<= 1)
#pragma unroll
            for (int r = 0; r < 4; ++r)
                rs[r] += __shfl_xor(rs[r], d, 16);
#pragma unroll
        for (int r = 0; r < 4; ++r) {
            l[r] += rs[r];
            int ql = hi * 4 + r;
            pl[ql * 32 + lo]      = bfbits(p0[r]);
            pl[ql * 32 + 16 + lo] = bfbits(p1[r]);
        }
        // P transpose via wave-private LDS -> PV A-frag (compiler inserts lgkmcnt)
        bf16x8 pa = *(const bf16x8*)(pl + lo * 32 + hi * 8);
        const unsigned short* vb = VT + (size_t)(b * NH + lo) * NT + s0 + hi * 8;
#pragma unroll
        for (int ct = 0; ct < 4; ++ct) {
            bf16x8 vv = *(const bf16x8*)(vb + ct * 16 * NT);
            acc[ct] = __builtin_amdgcn_mfma_f32_16x16x32_bf16(pa, vv, acc[ct], 0, 0, 0);
        }
    }

    // dump per-wave partial state
#pragma unroll
    for (int r = 0; r < 4; ++r) {
        int ql = hi * 4 + r;
#pragma unroll
        for (int ct = 0; ct < 4; ++ct)
            acc_lds[(w * 16 + ql) * 64 + lo + 16 * ct] = acc[ct][r];
    }
    if (lo == 0) {
#pragma unroll
        for (int r = 0; r < 4; ++r) {
            m_lds[w][hi * 4 + r] = m[r];
            l_lds[w][hi * 4 + r] = l[r];
        }
    }
    __syncthreads();

    // merge 4 s-splits: thread -> (q, 4 h's)
    int q  = threadIdx.x >> 4;
    int h0 = (threadIdx.x & 15) << 2;
    float M = fmaxf(fmaxf(m_lds[0][q], m_lds[1][q]), fmaxf(m_lds[2][q], m_lds[3][q]));
    float L = 0.f;
    float ox = 0.f, oy = 0.f, oz = 0.f, ow = 0.f;
#pragma unroll
    for (int ww = 0; ww < 4; ++ww) {
        float a_ = exp2f(m_lds[ww][q] - M);
        L += a_ * l_lds[ww][q];
        const float* p = acc_lds + (ww * 16 + q) * 64 + h0;
        ox += a_ * p[0]; oy += a_ * p[1]; oz += a_ * p[2]; ow += a_ * p[3];
    }
    float inv = 1.0f / L;
    float4 res = make_float4(ox * inv, oy * inv, oz * inv, ow * inv);
    *(float4*)(out + (size_t)(b * NT + q0 + q) * NH + h0) = res;
}

extern "C" void kernel_launch(void* const* d_in, const int* in_sizes, int n_in,
                              void* d_out, int out_size, void* d_ws, size_t ws_size,
                              hipStream_t stream) {
    const float* values  = (const float*)d_in[0];
    const float* keys    = (const float*)d_in[1];
    const float* queries = (const float*)d_in[2];
    const float* Wk = (const float*)d_in[3];
    const float* Wq = (const float*)d_in[4];
    const float* Wv = (const float*)d_in[5];
    float* out = (float*)d_out;

    unsigned short* Wt = (unsigned short*)d_ws;        // 196608 ushorts
    unsigned short* Qb = Wt + 196608;                  // Q,K,VT: 3x1048576 ushorts
    unsigned short* Kb = Qb + 1048576;
    unsigned short* VT = Kb + 1048576;

    wt_kernel<<<768, 256, 0, stream>>>(Wq, Wk, Wv, Wt);
    proj_kernel<<<768, 256, 0, stream>>>(values, keys, queries, Wt, Qb, Kb, VT);
    attn_kernel<<<1024, 256, 0, stream>>>(Qb, Kb, VT, out);
}

// Round 5
// 101.201 us; speedup vs baseline: 1.4164x; 1.0034x over previous
//
#include <hip/hip_runtime.h>
#include <hip/hip_bf16.h>

typedef __bf16 bf16x8 __attribute__((ext_vector_type(8)));
typedef float f32x4 __attribute__((ext_vector_type(4)));

#define NB 8
#define NT 2048
#define NC 1024
#define NH 64

__device__ __forceinline__ unsigned short bfbits(float f) {
    return __builtin_bit_cast(unsigned short, (__bf16)f);
}

__device__ __forceinline__ void gl_lds16(const void* g, void* l) {
    __builtin_amdgcn_global_load_lds(
        (const __attribute__((address_space(1))) void*)g,
        (__attribute__((address_space(3))) void*)l, 16, 0, 0);
}

// ---------------- kernel 1: W -> W^T (bf16) ----------------
// Wt layout: [3][64][1024], order 0=Wq, 1=Wk, 2=Wv
__global__ __launch_bounds__(256) void wt_kernel(const float* __restrict__ Wq,
                                                 const float* __restrict__ Wk,
                                                 const float* __restrict__ Wv,
                                                 unsigned short* __restrict__ Wt) {
    int idx = blockIdx.x * 256 + threadIdx.x;   // 0 .. 196608
    int n = idx >> 16;
    int r = idx & 65535;
    int c = r >> 6;       // 0..1023
    int h = r & 63;       // coalesced reads over h
    const float* W = (n == 0) ? Wq : ((n == 1) ? Wk : Wv);
    float x = W[c * 64 + h];
    Wt[(n << 16) + h * 1024 + c] = bfbits(x);
}

// ---------------- kernel 2: LDS-staged tiled QKV projection ----------------
// block = 256 thr (4 waves), BM=64 rows, BK=128, K=1024 (8 chunks)
// LDS: Xs = 64 rows x 128 f32 (512B/row, 32KB), Ws = 64 h x 128 bf16 (256B/row, 16KB)
// Staged via global_load_lds (linear dest) with pre-swizzled global source;
// reads apply the same XOR ((row&7)<<4) -> 2-way bank aliasing (free).
__global__ __launch_bounds__(256, 3) void proj_kernel(const float* __restrict__ Xv,
                                                      const float* __restrict__ Xk,
                                                      const float* __restrict__ Xq,
                                                      const unsigned short* __restrict__ Wt,
                                                      unsigned short* __restrict__ Q,
                                                      unsigned short* __restrict__ K,
                                                      unsigned short* __restrict__ VT) {
    __shared__ __align__(16) char Xs[64 * 512];   // fp32 tile
    __shared__ __align__(16) char Ws[64 * 256];   // bf16 tile

    int type = blockIdx.x >> 8;          // 0=Q,1=K,2=V
    int mt   = blockIdx.x & 255;         // 64-row tile over 16384 rows
    int row0 = mt << 6;
    const float* X = (type == 0) ? Xq : ((type == 1) ? Xk : Xv);

    int tid  = threadIdx.x;
    int w    = tid >> 6;
    int lane = tid & 63;
    int lo = lane & 15, hi = lane >> 4;
    int swz = (lo & 7) << 4;

    const char* Xbase = (const char*)X + (size_t)row0 * 4096;
    const char* Wbase = (const char*)(Wt + (type << 16));

    // per-lane pre-swizzled source offsets (constant across chunks)
    int xr = 2 * (w * 8) + (lane >> 5);          // row of this wave's first X granule
    int xcb = (lane & 31) * 16;                  // byte col within 512B row
    int wr = 4 * (w * 4) + (lane >> 4);          // row of this wave's first W granule
    int wcb = (lane & 15) * 16;                  // byte col within 256B row

    f32x4 acc[4];
#pragma unroll
    for (int ct = 0; ct < 4; ++ct) acc[ct] = 0.f;

    for (int kc = 0; kc < 8; ++kc) {
        if (kc) __syncthreads();      // prev MFMA done before LDS overwrite
        // ---- stage X: 8 granules/wave of 1KB (2 rows x 512B each) ----
#pragma unroll
        for (int i = 0; i < 8; ++i) {
            int g = w * 8 + i;
            int r = xr + 2 * i;
            gl_lds16(Xbase + (size_t)r * 4096 + kc * 512 + (xcb ^ ((r & 7) << 4)),
                     Xs + g * 1024);
        }
        // ---- stage W: 4 granules/wave of 1KB (4 rows x 256B each) ----
#pragma unroll
        for (int i = 0; i < 4; ++i) {
            int g = w * 4 + i;
            int r = wr + 4 * i;
            gl_lds16(Wbase + (size_t)r * 2048 + kc * 256 + (wcb ^ ((r & 7) << 4)),
                     Ws + g * 1024);
        }
        asm volatile("s_waitcnt vmcnt(0)" ::: "memory");
        __syncthreads();
        // ---- 4 k-steps of 32 ----
#pragma unroll
        for (int ks = 0; ks < 4; ++ks) {
            float4 a0 = *(const float4*)(Xs + (w * 16 + lo) * 512 + ((ks * 128 + hi * 32) ^ swz));
            float4 a1 = *(const float4*)(Xs + (w * 16 + lo) * 512 + ((ks * 128 + hi * 32 + 16) ^ swz));
            bf16x8 af;
            af[0] = (__bf16)a0.x; af[1] = (__bf16)a0.y; af[2] = (__bf16)a0.z; af[3] = (__bf16)a0.w;
            af[4] = (__bf16)a1.x; af[5] = (__bf16)a1.y; af[6] = (__bf16)a1.z; af[7] = (__bf16)a1.w;
#pragma unroll
            for (int ct = 0; ct < 4; ++ct) {
                bf16x8 bf = *(const bf16x8*)(Ws + (ct * 16 + lo) * 256 + ((ks * 64 + hi * 16) ^ swz));
                acc[ct] = __builtin_amdgcn_mfma_f32_16x16x32_bf16(af, bf, acc[ct], 0, 0, 0);
            }
        }
    }

    // ---- epilogue ----
    if (type < 2) {
        unsigned short* O = (type == 0) ? Q : K;
#pragma unroll
        for (int ct = 0; ct < 4; ++ct)
#pragma unroll
            for (int r = 0; r < 4; ++r) {
                int row = row0 + w * 16 + hi * 4 + r;
                int h = lo + 16 * ct;
                O[(size_t)row * NH + h] = bfbits(acc[ct][r]);
            }
    } else {
        int trow = row0 + w * 16 + hi * 4;       // 4-aligned
        int b = trow >> 11;
        int t = trow & 2047;
#pragma unroll
        for (int ct = 0; ct < 4; ++ct) {
            int h = lo + 16 * ct;
            ushort4 pk;
            pk.x = bfbits(acc[ct][0]);
            pk.y = bfbits(acc[ct][1]);
            pk.z = bfbits(acc[ct][2]);
            pk.w = bfbits(acc[ct][3]);
            *(ushort4*)(VT + (size_t)(b * NH + h) * NT + t) = pk;
        }
    }
}

// ---------------- kernel 3: causal flash attention (MFMA) ----------------
// block = 4 waves, one 16-row Q-tile, 4-way split of the s-range + LDS merge
__global__ __launch_bounds__(256) void attn_kernel(const unsigned short* __restrict__ Q,
                                                   const unsigned short* __restrict__ K,
                                                   const unsigned short* __restrict__ VT,
                                                   float* __restrict__ out) {
    __shared__ __align__(16) unsigned short p_lds[4 * 512];   // per-wave 16x32 bf16 P
    __shared__ __align__(16) float acc_lds[4 * 16 * 64];
    __shared__ float m_lds[4][16];
    __shared__ float l_lds[4][16];

    int b  = blockIdx.x >> 7;
    int qt = blockIdx.x & 127;
    int q0 = qt << 4;
    int w    = threadIdx.x >> 6;
    int lane = threadIdx.x & 63;
    int lo = lane & 15, hi = lane >> 4;

    const unsigned short* qb = Q + (size_t)(b * NT + q0 + lo) * NH + hi * 8;
    bf16x8 qf0 = *(const bf16x8*)(qb);
    bf16x8 qf1 = *(const bf16x8*)(qb + 32);

    int Ctot = (q0 + 16 + 31) >> 5;              // ceil((q0+16)/32) 32-wide s-chunks
    int c0 = (Ctot * w) >> 2;
    int c1 = (Ctot * (w + 1)) >> 2;

    float m[4], l[4];
    f32x4 acc[4];
#pragma unroll
    for (int r = 0; r < 4; ++r) { m[r] = -1e30f; l[r] = 0.f; }
#pragma unroll
    for (int ct = 0; ct < 4; ++ct) acc[ct] = 0.f;

    const float SC = 0.03125f * 1.44269504088896340736f;  // (C^-0.5) * log2(e)
    unsigned short* pl = p_lds + w * 512;

    for (int c = c0; c < c1; ++c) {
        int s0 = c << 5;
        const unsigned short* kb = K + (size_t)(b * NT + s0 + lo) * NH + hi * 8;
        f32x4 S0 = 0.f, S1 = 0.f;
        S0 = __builtin_amdgcn_mfma_f32_16x16x32_bf16(qf0, *(const bf16x8*)(kb), S0, 0, 0, 0);
        S0 = __builtin_amdgcn_mfma_f32_16x16x32_bf16(qf1, *(const bf16x8*)(kb + 32), S0, 0, 0, 0);
        S1 = __builtin_amdgcn_mfma_f32_16x16x32_bf16(qf0, *(const bf16x8*)(kb + 16 * NH), S1, 0, 0, 0);
        S1 = __builtin_amdgcn_mfma_f32_16x16x32_bf16(qf1, *(const bf16x8*)(kb + 16 * NH + 32), S1, 0, 0, 0);

        int s_a = s0 + lo, s_b = s0 + 16 + lo;
        float z0[4], z1[4], mt[4];
#pragma unroll
        for (int r = 0; r < 4; ++r) {
            int qi = q0 + hi * 4 + r;
            z0[r] = (s_a <= qi) ? S0[r] * SC : -1e30f;
            z1[r] = (s_b <= qi) ? S1[r] * SC : -1e30f;
            mt[r] = fmaxf(z0[r], z1[r]);
        }
#pragma unroll
        for (int d = 1; d < 16; d <<= 1)
#pragma unroll
            for (int r = 0; r < 4; ++r)
                mt[r] = fmaxf(mt[r], __shfl_xor(mt[r], d, 16));

        float p0[4], p1[4], rs[4];
#pragma unroll
        for (int r = 0; r < 4; ++r) {
            float mn = fmaxf(m[r], mt[r]);
            float al = exp2f(m[r] - mn);
            int qi = q0 + hi * 4 + r;
            p0[r] = (s_a <= qi) ? exp2f(z0[r] - mn) : 0.f;
            p1[r] = (s_b <= qi) ? exp2f(z1[r] - mn) : 0.f;
            rs[r] = p0[r] + p1[r];
            m[r] = mn;
            l[r] *= al;
            acc[0][r] *= al; acc[1][r] *= al; acc[2][r] *= al; acc[3][r] *= al;
        }
#pragma unroll
        for (int d = 1; d < 16; d <<= 1)
#pragma unroll
            for (int r = 0; r < 4; ++r)
                rs[r] += __shfl_xor(rs[r], d, 16);
#pragma unroll
        for (int r = 0; r < 4; ++r) {
            l[r] += rs[r];
            int ql = hi * 4 + r;
            pl[ql * 32 + lo]      = bfbits(p0[r]);
            pl[ql * 32 + 16 + lo] = bfbits(p1[r]);
        }
        // P transpose via wave-private LDS -> PV A-frag (compiler inserts lgkmcnt)
        bf16x8 pa = *(const bf16x8*)(pl + lo * 32 + hi * 8);
        const unsigned short* vb = VT + (size_t)(b * NH + lo) * NT + s0 + hi * 8;
#pragma unroll
        for (int ct = 0; ct < 4; ++ct) {
            bf16x8 vv = *(const bf16x8*)(vb + ct * 16 * NT);
            acc[ct] = __builtin_amdgcn_mfma_f32_16x16x32_bf16(pa, vv, acc[ct], 0, 0, 0);
        }
    }

    // dump per-wave partial state
#pragma unroll
    for (int r = 0; r < 4; ++r) {
        int ql = hi * 4 + r;
#pragma unroll
        for (int ct = 0; ct < 4; ++ct)
            acc_lds[(w * 16 + ql) * 64 + lo + 16 * ct] = acc[ct][r];
    }
    if (lo == 0) {
#pragma unroll
        for (int r = 0; r < 4; ++r) {
            m_lds[w][hi * 4 + r] = m[r];
            l_lds[w][hi * 4 + r] = l[r];
        }
    }
    __syncthreads();

    // merge 4 s-splits: thread -> (q, 4 h's)
    int q  = threadIdx.x >> 4;
    int h0 = (threadIdx.x & 15) << 2;
    float M = fmaxf(fmaxf(m_lds[0][q], m_lds[1][q]), fmaxf(m_lds[2][q], m_lds[3][q]));
    float L = 0.f;
    float ox = 0.f, oy = 0.f, oz = 0.f, ow = 0.f;
#pragma unroll
    for (int ww = 0; ww < 4; ++ww) {
        float a_ = exp2f(m_lds[ww][q] - M);
        L += a_ * l_lds[ww][q];
        const float* p = acc_lds + (ww * 16 + q) * 64 + h0;
        ox += a_ * p[0]; oy += a_ * p[1]; oz += a_ * p[2]; ow += a_ * p[3];
    }
    float inv = 1.0f / L;
    float4 res = make_float4(ox * inv, oy * inv, oz * inv, ow * inv);
    *(float4*)(out + (size_t)(b * NT + q0 + q) * NH + h0) = res;
}

extern "C" void kernel_launch(void* const* d_in, const int* in_sizes, int n_in,
                              void* d_out, int out_size, void* d_ws, size_t ws_size,
                              hipStream_t stream) {
    const float* values  = (const float*)d_in[0];
    const float* keys    = (const float*)d_in[1];
    const float* queries = (const float*)d_in[2];
    const float* Wk = (const float*)d_in[3];
    const float* Wq = (const float*)d_in[4];
    const float* Wv = (const float*)d_in[5];
    float* out = (float*)d_out;

    unsigned short* Wt = (unsigned short*)d_ws;        // 196608 ushorts
    unsigned short* Qb = Wt + 196608;                  // Q,K,VT: 3x1048576 ushorts
    unsigned short* Kb = Qb + 1048576;
    unsigned short* VT = Kb + 1048576;

    wt_kernel<<<768, 256, 0, stream>>>(Wq, Wk, Wv, Wt);
    proj_kernel<<<768, 256, 0, stream>>>(values, keys, queries, Wt, Qb, Kb, VT);
    attn_kernel<<<1024, 256, 0, stream>>>(Qb, Kb, VT, out);
}

// Round 6
// 100.391 us; speedup vs baseline: 1.4278x; 1.0081x over previous
//
#include <hip/hip_runtime.h>
#include <hip/hip_bf16.h>

typedef __bf16 bf16x8 __attribute__((ext_vector_type(8)));
typedef float f32x4 __attribute__((ext_vector_type(4)));

#define NB 8
#define NT 2048
#define NC 1024
#define NH 64

__device__ __forceinline__ unsigned short bfbits(float f) {
    return __builtin_bit_cast(unsigned short, (__bf16)f);
}

__device__ __forceinline__ void gl_lds16(const void* g, void* l) {
    __builtin_amdgcn_global_load_lds(
        (const __attribute__((address_space(1))) void*)g,
        (__attribute__((address_space(3))) void*)l, 16, 0, 0);
}

// ---------------- kernel 1: W -> W^T (bf16) ----------------
// Wt layout: [3][64][1024], order 0=Wq, 1=Wk, 2=Wv
__global__ __launch_bounds__(256) void wt_kernel(const float* __restrict__ Wq,
                                                 const float* __restrict__ Wk,
                                                 const float* __restrict__ Wv,
                                                 unsigned short* __restrict__ Wt) {
    int idx = blockIdx.x * 256 + threadIdx.x;   // 0 .. 196608
    int n = idx >> 16;
    int r = idx & 65535;
    int c = r >> 6;       // 0..1023
    int h = r & 63;       // coalesced reads over h
    const float* W = (n == 0) ? Wq : ((n == 1) ? Wk : Wv);
    float x = W[c * 64 + h];
    Wt[(n << 16) + h * 1024 + c] = bfbits(x);
}

// ---------------- kernel 2: pipelined LDS-staged QKV projection ----------------
// block = 4 waves, BM=64, BK=64, 16 k-chunks processed in block-staggered order.
// Double-buffered LDS, counted vmcnt(6), raw s_barrier (loads span barriers).
// LDS: Xs[2] = 64rows x 256B fp32 (16KB), Ws[2] = 64h x 128B bf16 (8KB) -> 48KB.
__global__ __launch_bounds__(256, 3) void proj_kernel(const float* __restrict__ Xv,
                                                      const float* __restrict__ Xk,
                                                      const float* __restrict__ Xq,
                                                      const unsigned short* __restrict__ Wt,
                                                      unsigned short* __restrict__ Q,
                                                      unsigned short* __restrict__ K,
                                                      unsigned short* __restrict__ VT) {
    __shared__ __align__(16) char Xs[2][16384];
    __shared__ __align__(16) char Ws[2][8192];

    int type = blockIdx.x >> 8;          // 0=Q,1=K,2=V
    int mt   = blockIdx.x & 255;
    int row0 = mt << 6;
    int phase = mt & 15;                 // k-chunk rotation (stagger)
    const float* X = (type == 0) ? Xq : ((type == 1) ? Xk : Xv);

    int tid  = threadIdx.x;
    int w    = tid >> 6;
    int lane = tid & 63;
    int lo = lane & 15, hi = lane >> 4;
    int swz = (lo & 7) << 4;

    const char* Xbase = (const char*)X + (size_t)row0 * 4096;
    const char* Wbase = (const char*)(Wt + (type << 16));

    // precomputed per-lane staging rows/cols (pre-swizzled global source, linear LDS dest)
    int xg0 = w * 4;                      // first X granule (of 4) for this wave
    int xr_l = lane >> 4;                 // row within granule
    int xc_l = (lane & 15) * 16;          // byte col within 256B chunk-row
    int wg0 = w * 2;                      // first W granule (of 2)
    int wr_l = lane >> 3;
    int wc_l = (lane & 7) * 16;

    f32x4 acc[4];
#pragma unroll
    for (int ct = 0; ct < 4; ++ct) acc[ct] = 0.f;

    auto stage = [&](int kc, int buf) {
#pragma unroll
        for (int i = 0; i < 4; ++i) {
            int g = xg0 + i;
            int r = g * 4 + xr_l;
            gl_lds16(Xbase + (size_t)r * 4096 + kc * 256 + (xc_l ^ ((r & 7) << 4)),
                     Xs[buf] + g * 1024);
        }
#pragma unroll
        for (int i = 0; i < 2; ++i) {
            int g = wg0 + i;
            int h = g * 8 + wr_l;
            gl_lds16(Wbase + (size_t)h * 2048 + kc * 128 + (wc_l ^ ((h & 7) << 4)),
                     Ws[buf] + g * 1024);
        }
    };

    auto compute = [&](int buf) {
        const char* xrow = Xs[buf] + (w * 16 + lo) * 256;
        const char* wb   = Ws[buf];
#pragma unroll
        for (int ks = 0; ks < 2; ++ks) {
            float4 a0 = *(const float4*)(xrow + ((ks * 128 + hi * 32) ^ swz));
            float4 a1 = *(const float4*)(xrow + ((ks * 128 + hi * 32 + 16) ^ swz));
            bf16x8 af;
            af[0] = (__bf16)a0.x; af[1] = (__bf16)a0.y; af[2] = (__bf16)a0.z; af[3] = (__bf16)a0.w;
            af[4] = (__bf16)a1.x; af[5] = (__bf16)a1.y; af[6] = (__bf16)a1.z; af[7] = (__bf16)a1.w;
#pragma unroll
            for (int ct = 0; ct < 4; ++ct) {
                bf16x8 bf = *(const bf16x8*)(wb + (ct * 16 + lo) * 128 + ((ks * 64 + hi * 16) ^ swz));
                acc[ct] = __builtin_amdgcn_mfma_f32_16x16x32_bf16(af, bf, acc[ct], 0, 0, 0);
            }
        }
    };

    // prologue: two chunks in flight
    stage(phase, 0);
    stage((1 + phase) & 15, 1);

    for (int c = 0; c < 16; ++c) {
        int buf = c & 1;
        if (c < 15) asm volatile("s_waitcnt vmcnt(6)" ::: "memory");
        else        asm volatile("s_waitcnt vmcnt(0)" ::: "memory");
        __builtin_amdgcn_s_barrier();      // whole tile of chunk c now in LDS
        compute(buf);
        if (c + 2 < 16) {
            __builtin_amdgcn_s_barrier();  // all waves done reading buf
            stage((c + 2 + phase) & 15, buf);
        }
    }

    // ---- epilogue ----
    if (type < 2) {
        unsigned short* O = (type == 0) ? Q : K;
#pragma unroll
        for (int ct = 0; ct < 4; ++ct)
#pragma unroll
            for (int r = 0; r < 4; ++r) {
                int row = row0 + w * 16 + hi * 4 + r;
                int h = lo + 16 * ct;
                O[(size_t)row * NH + h] = bfbits(acc[ct][r]);
            }
    } else {
        int trow = row0 + w * 16 + hi * 4;       // 4-aligned
        int b = trow >> 11;
        int t = trow & 2047;
#pragma unroll
        for (int ct = 0; ct < 4; ++ct) {
            int h = lo + 16 * ct;
            ushort4 pk;
            pk.x = bfbits(acc[ct][0]);
            pk.y = bfbits(acc[ct][1]);
            pk.z = bfbits(acc[ct][2]);
            pk.w = bfbits(acc[ct][3]);
            *(ushort4*)(VT + (size_t)(b * NH + h) * NT + t) = pk;
        }
    }
}

// ---------------- kernel 3: causal flash attention (MFMA) ----------------
// block = 4 waves, one 16-row Q-tile, 4-way split of the s-range + LDS merge
__global__ __launch_bounds__(256) void attn_kernel(const unsigned short* __restrict__ Q,
                                                   const unsigned short* __restrict__ K,
                                                   const unsigned short* __restrict__ VT,
                                                   float* __restrict__ out) {
    __shared__ __align__(16) unsigned short p_lds[4 * 512];   // per-wave 16x32 bf16 P
    __shared__ __align__(16) float acc_lds[4 * 16 * 64];
    __shared__ float m_lds[4][16];
    __shared__ float l_lds[4][16];

    int b  = blockIdx.x >> 7;
    int qt = blockIdx.x & 127;
    int q0 = qt << 4;
    int w    = threadIdx.x >> 6;
    int lane = threadIdx.x & 63;
    int lo = lane & 15, hi = lane >> 4;

    const unsigned short* qb = Q + (size_t)(b * NT + q0 + lo) * NH + hi * 8;
    bf16x8 qf0 = *(const bf16x8*)(qb);
    bf16x8 qf1 = *(const bf16x8*)(qb + 32);

    int Ctot = (q0 + 16 + 31) >> 5;              // ceil((q0+16)/32) 32-wide s-chunks
    int c0 = (Ctot * w) >> 2;
    int c1 = (Ctot * (w + 1)) >> 2;

    float m[4], l[4];
    f32x4 acc[4];
#pragma unroll
    for (int r = 0; r < 4; ++r) { m[r] = -1e30f; l[r] = 0.f; }
#pragma unroll
    for (int ct = 0; ct < 4; ++ct) acc[ct] = 0.f;

    const float SC = 0.03125f * 1.44269504088896340736f;  // (C^-0.5) * log2(e)
    unsigned short* pl = p_lds + w * 512;

    for (int c = c0; c < c1; ++c) {
        int s0 = c << 5;
        const unsigned short* kb = K + (size_t)(b * NT + s0 + lo) * NH + hi * 8;
        f32x4 S0 = 0.f, S1 = 0.f;
        S0 = __builtin_amdgcn_mfma_f32_16x16x32_bf16(qf0, *(const bf16x8*)(kb), S0, 0, 0, 0);
        S0 = __builtin_amdgcn_mfma_f32_16x16x32_bf16(qf1, *(const bf16x8*)(kb + 32), S0, 0, 0, 0);
        S1 = __builtin_amdgcn_mfma_f32_16x16x32_bf16(qf0, *(const bf16x8*)(kb + 16 * NH), S1, 0, 0, 0);
        S1 = __builtin_amdgcn_mfma_f32_16x16x32_bf16(qf1, *(const bf16x8*)(kb + 16 * NH + 32), S1, 0, 0, 0);

        int s_a = s0 + lo, s_b = s0 + 16 + lo;
        float z0[4], z1[4], mt[4];
#pragma unroll
        for (int r = 0; r < 4; ++r) {
            int qi = q0 + hi * 4 + r;
            z0[r] = (s_a <= qi) ? S0[r] * SC : -1e30f;
            z1[r] = (s_b <= qi) ? S1[r] * SC : -1e30f;
            mt[r] = fmaxf(z0[r], z1[r]);
        }
#pragma unroll
        for (int d = 1; d < 16; d <<= 1)
#pragma unroll
            for (int r = 0; r < 4; ++r)
                mt[r] = fmaxf(mt[r], __shfl_xor(mt[r], d, 16));

        float p0[4], p1[4], rs[4];
#pragma unroll
        for (int r = 0; r < 4; ++r) {
            float mn = fmaxf(m[r], mt[r]);
            float al = exp2f(m[r] - mn);
            int qi = q0 + hi * 4 + r;
            p0[r] = (s_a <= qi) ? exp2f(z0[r] - mn) : 0.f;
            p1[r] = (s_b <= qi) ? exp2f(z1[r] - mn) : 0.f;
            rs[r] = p0[r] + p1[r];
            m[r] = mn;
            l[r] *= al;
            acc[0][r] *= al; acc[1][r] *= al; acc[2][r] *= al; acc[3][r] *= al;
        }
#pragma unroll
        for (int d = 1; d < 16; d <<= 1)
#pragma unroll
            for (int r = 0; r < 4; ++r)
                rs[r] += __shfl_xor(rs[r], d, 16);
#pragma unroll
        for (int r = 0; r < 4; ++r) {
            l[r] += rs[r];
            int ql = hi * 4 + r;
            pl[ql * 32 + lo]      = bfbits(p0[r]);
            pl[ql * 32 + 16 + lo] = bfbits(p1[r]);
        }
        // P transpose via wave-private LDS -> PV A-frag (compiler inserts lgkmcnt)
        bf16x8 pa = *(const bf16x8*)(pl + lo * 32 + hi * 8);
        const unsigned short* vb = VT + (size_t)(b * NH + lo) * NT + s0 + hi * 8;
#pragma unroll
        for (int ct = 0; ct < 4; ++ct) {
            bf16x8 vv = *(const bf16x8*)(vb + ct * 16 * NT);
            acc[ct] = __builtin_amdgcn_mfma_f32_16x16x32_bf16(pa, vv, acc[ct], 0, 0, 0);
        }
    }

    // dump per-wave partial state
#pragma unroll
    for (int r = 0; r < 4; ++r) {
        int ql = hi * 4 + r;
#pragma unroll
        for (int ct = 0; ct < 4; ++ct)
            acc_lds[(w * 16 + ql) * 64 + lo + 16 * ct] = acc[ct][r];
    }
    if (lo == 0) {
#pragma unroll
        for (int r = 0; r < 4; ++r) {
            m_lds[w][hi * 4 + r] = m[r];
            l_lds[w][hi * 4 + r] = l[r];
        }
    }
    __syncthreads();

    // merge 4 s-splits: thread -> (q, 4 h's)
    int q  = threadIdx.x >> 4;
    int h0 = (threadIdx.x & 15) << 2;
    float M = fmaxf(fmaxf(m_lds[0][q], m_lds[1][q]), fmaxf(m_lds[2][q], m_lds[3][q]));
    float L = 0.f;
    float ox = 0.f, oy = 0.f, oz = 0.f, ow = 0.f;
#pragma unroll
    for (int ww = 0; ww < 4; ++ww) {
        float a_ = exp2f(m_lds[ww][q] - M);
        L += a_ * l_lds[ww][q];
        const float* p = acc_lds + (ww * 16 + q) * 64 + h0;
        ox += a_ * p[0]; oy += a_ * p[1]; oz += a_ * p[2]; ow += a_ * p[3];
    }
    float inv = 1.0f / L;
    float4 res = make_float4(ox * inv, oy * inv, oz * inv, ow * inv);
    *(float4*)(out + (size_t)(b * NT + q0 + q) * NH + h0) = res;
}

extern "C" void kernel_launch(void* const* d_in, const int* in_sizes, int n_in,
                              void* d_out, int out_size, void* d_ws, size_t ws_size,
                              hipStream_t stream) {
    const float* values  = (const float*)d_in[0];
    const float* keys    = (const float*)d_in[1];
    const float* queries = (const float*)d_in[2];
    const float* Wk = (const float*)d_in[3];
    const float* Wq = (const float*)d_in[4];
    const float* Wv = (const float*)d_in[5];
    float* out = (float*)d_out;

    unsigned short* Wt = (unsigned short*)d_ws;        // 196608 ushorts
    unsigned short* Qb = Wt + 196608;                  // Q,K,VT: 3x1048576 ushorts
    unsigned short* Kb = Qb + 1048576;
    unsigned short* VT = Kb + 1048576;

    wt_kernel<<<768, 256, 0, stream>>>(Wq, Wk, Wv, Wt);
    proj_kernel<<<768, 256, 0, stream>>>(values, keys, queries, Wt, Qb, Kb, VT);
    attn_kernel<<<1024, 256, 0, stream>>>(Qb, Kb, VT, out);
}